// Round 8
// baseline (275.032 us; speedup 1.0000x reference)
//
#include <hip/hip_runtime.h>
#include <hip/hip_fp16.h>
#include <stdint.h>

// AdaptiveGCN: B=8, L=128, D=768.  All-f16 MFMA pipeline.
// Algebra: denom==2.0 exactly; mask==all-False; (ax+out)@gw+2gb == ((a+I)@out)@gw+2gb;
// concat-linear splits into hi = x@w1[:D], hj = x@w1[D:];
// LN fused into next layer's A: (a+I)@LN(y) = lng*((a'*rstd)@y - c) + 2*lnb.
// R8: edge = dbuf W-DMA (drain off critical path) + XOR-swizzled sH (0 conflicts);
//     GCN = A1/A2/A3 with fused LN + yT packed stores + final LN kernel. 7 launches.

typedef __attribute__((ext_vector_type(8))) _Float16 half8;
typedef __attribute__((ext_vector_type(2))) _Float16 half2v;
typedef __attribute__((ext_vector_type(2))) __fp16 fp16x2;   // cvt_pkrtz ret type
typedef __attribute__((ext_vector_type(4))) float floatx4;

__device__ __forceinline__ unsigned short f2h(float f) {
    union { fp16x2 p; unsigned short s[2]; } v;
    v.p = __builtin_amdgcn_cvt_pkrtz(f, f);
    return v.s[0];
}
__device__ __forceinline__ half2v f2h2v(float a, float b) {
    union { fp16x2 p; half2v h; } v;
    v.p = __builtin_amdgcn_cvt_pkrtz(a, b);
    return v.h;
}
__device__ __forceinline__ float h2f(unsigned short u) {
    union { unsigned short u; _Float16 h; } c; c.u = u;
    return (float)c.h;
}
__device__ __forceinline__ floatx4 mfma16(half8 a, half8 b, floatx4 c) {
    return __builtin_amdgcn_mfma_f32_16x16x32_f16(a, b, c, 0, 0, 0);
}
__device__ __forceinline__ void gload16(const void* g, void* lds) {
    __builtin_amdgcn_global_load_lds(
        (const __attribute__((address_space(1))) void*)g,
        (__attribute__((address_space(3))) void*)lds, 16, 0, 0);
}

// B-fragment pack: tile(s = k-chunk32, ntile = n-group16) = 512 shorts;
// element (n_local, k_local) at lane=(k_local>>3)*16+n_local, e=k_local&7.

// ---------------- prep: all weight conversions / packings -------------------
__global__ void prep_kernel(const float* __restrict__ x, const float* __restrict__ w1,
                            const float* __restrict__ w2, const float* __restrict__ gw,
                            unsigned short* __restrict__ w1t,
                            unsigned short* __restrict__ w2p,
                            unsigned short* __restrict__ gwp,
                            unsigned short* __restrict__ xh,
                            unsigned short* __restrict__ xpk,
                            float* __restrict__ maskout) {
    const int z = blockIdx.z;
    const int tx = threadIdx.x, ty = threadIdx.y;  // 32 x 8
    const int t = ty * 32 + tx;

    if (z == 5) {  // w2 (768x384 fp32 [k][n]) -> w2p frag tiles (s*24+ntg)*512
        const int s = blockIdx.x, ntg = blockIdx.y;  // both 0..23
        const int lane = t >> 2, e0 = (t & 3) * 2;
        const int n = ntg * 16 + (lane & 15);
        const int kbase = s * 32 + (lane >> 4) * 8;
        unsigned short* dst = w2p + (s * 24 + ntg) * 512 + lane * 8 + e0;
        dst[0] = f2h(w2[(kbase + e0) * 384 + n]);
        dst[1] = f2h(w2[(kbase + e0 + 1) * 384 + n]);
        return;
    }
    if (z == 6) {  // x fp32 -> f16 row-major, plus zero the mask outputs
        int gid = (blockIdx.y * 24 + blockIdx.x) * 256 + t;
        for (int i = gid; i < 786432; i += 24 * 24 * 256) xh[i] = f2h(x[i]);
        if (gid < 1024) maskout[gid] = 0.f;
        return;
    }
    if (z < 2) {  // w1 halves: transpose 768x768 fp32 -> f16 [n][k]
        const float* src = w1 + z * 589824;
        unsigned short* dst = w1t + z * 589824;
        const int c0 = blockIdx.x * 32, r0 = blockIdx.y * 32;
        __shared__ float tile[32][33];
        #pragma unroll
        for (int yy = ty; yy < 32; yy += 8)
            tile[yy][tx] = src[(r0 + yy) * 768 + (c0 + tx)];
        __syncthreads();
        #pragma unroll
        for (int yy = ty; yy < 32; yy += 8)
            dst[(c0 + yy) * 768 + (r0 + tx)] = f2h(tile[tx][yy]);
        return;
    }
    // frag-pack paths: z=2..4 -> gw layer (768x768 [k][n]); z=7..14 -> x batch
    const float* src; unsigned short* dstb; long tprefix; int rows;
    if (z <= 4) {
        int li = z - 2;
        src = gw + li * 589824; dstb = gwp + (long)li * 589824;
        tprefix = 0; rows = 768;
    } else {
        int bz = z - 7;
        src = x + bz * 98304; dstb = xpk;
        tprefix = (long)bz * 4; rows = 128;
    }
    const int c0 = blockIdx.x * 32, r0 = blockIdx.y * 32;
    if (r0 >= rows) return;
    __shared__ float tile[32][33];
    #pragma unroll
    for (int yy = ty; yy < 32; yy += 8)
        tile[yy][tx] = src[(r0 + yy) * 768 + (c0 + tx)];
    __syncthreads();
    if (t < 128) {
        const int n_off = t & 31, kg = t >> 5;
        const int s = r0 >> 5;
        long tileIdx = (tprefix + s) * 48 + (c0 >> 4) + (n_off >> 4);
        unsigned short* dst = dstb + tileIdx * 512 + (kg * 16 + (n_off & 15)) * 8;
        union { uint4 u; unsigned short s[8]; } pk;
        #pragma unroll
        for (int e = 0; e < 8; ++e) pk.s[e] = f2h(tile[kg * 8 + e][n_off]);
        *(uint4*)dst = pk.u;
    }
}

// --------- 128x128-tile f16 GEMM: hi|hj = x @ [w1_top|w1_bot]^T -------------
__global__ __launch_bounds__(256) void gemm128_kernel(
    const unsigned short* __restrict__ A, const unsigned short* __restrict__ Bm,
    float* __restrict__ hi, unsigned short* __restrict__ hjh) {
    __shared__ __align__(16) unsigned short sA[128 * 32];
    __shared__ __align__(16) unsigned short sB[128 * 32];
    const int n0 = blockIdx.x * 128, m0 = blockIdx.y * 128;
    const int t = threadIdx.x, wave = t >> 6, lane = t & 63;
    const int wm = wave >> 1, wn = wave & 1, col = lane & 15, q = lane >> 4;

    floatx4 acc[4][4];
    #pragma unroll
    for (int mt = 0; mt < 4; ++mt)
        #pragma unroll
        for (int nt = 0; nt < 4; ++nt) acc[mt][nt] = (floatx4){0.f, 0.f, 0.f, 0.f};

    for (int k0 = 0; k0 < 768; k0 += 32) {
        #pragma unroll
        for (int c = 0; c < 2; ++c) {
            int cid = (wave * 2 + c) * 64 + lane;
            int rw = cid >> 2;
            int half = (cid & 3) ^ ((rw >> 1) & 3);
            gload16(A + (m0 + rw) * 768 + k0 + half * 8, (char*)sA + (wave * 2 + c) * 1024);
            gload16(Bm + (n0 + rw) * 768 + k0 + half * 8, (char*)sB + (wave * 2 + c) * 1024);
        }
        __syncthreads();
        half8 aF[4], bF[4];
        #pragma unroll
        for (int mt = 0; mt < 4; ++mt) {
            int r = wm * 64 + mt * 16 + col;
            aF[mt] = *(const half8*)&sA[r * 32 + (q ^ ((r >> 1) & 3)) * 8];
        }
        #pragma unroll
        for (int nt = 0; nt < 4; ++nt) {
            int r = wn * 64 + nt * 16 + col;
            bF[nt] = *(const half8*)&sB[r * 32 + (q ^ ((r >> 1) & 3)) * 8];
        }
        #pragma unroll
        for (int mt = 0; mt < 4; ++mt)
            #pragma unroll
            for (int nt = 0; nt < 4; ++nt)
                acc[mt][nt] = mfma16(aF[mt], bF[nt], acc[mt][nt]);
        __syncthreads();
    }
    #pragma unroll
    for (int mt = 0; mt < 4; ++mt)
        #pragma unroll
        for (int nt = 0; nt < 4; ++nt) {
            int mg = m0 + wm * 64 + mt * 16 + q * 4;
            int ng = n0 + wn * 64 + nt * 16 + col;
            if (ng < 768) {
                #pragma unroll
                for (int r = 0; r < 4; ++r) hi[(mg + r) * 768 + ng] = acc[mt][nt][r];
            } else {
                #pragma unroll
                for (int r = 0; r < 4; ++r) hjh[(mg + r) * 768 + (ng - 768)] = f2h(acc[mt][nt][r]);
            }
        }
}

// ------------- edge kernel: one block per (b,i); fused row -------------------
// 256 thr = 4 waves, each wave 96 N-cols (acc[8][6]).  K-loop: dbuf W DMA
// (issued one step ahead -> barrier drain is off critical path), XOR-swizzled sH.
__global__ __launch_bounds__(256, 2) void edge_kernel(
    const float* __restrict__ hi, const unsigned short* __restrict__ hjh,
    const float* __restrict__ b1, const unsigned short* __restrict__ w2p,
    const float* __restrict__ b2, const float* __restrict__ w3,
    const float* __restrict__ b3, const float* __restrict__ adj,
    unsigned short* __restrict__ ah, float* __restrict__ statsAll) {
    __shared__ __align__(16) unsigned short sW[2][24 * 512];  // 48KB dbuf
    __shared__ __align__(16) unsigned short sH[128 * 32];     // 8KB, XOR swizzle
    __shared__ __align__(16) half2v sHib[384];
    __shared__ float sEw[128];
    __shared__ float sRed[4];

    const int t = threadIdx.x;
    const int row_i = blockIdx.x;
    const int b = row_i >> 7, i = row_i & 127;

    if (blockIdx.x < 24) statsAll[blockIdx.x * 256 + t] = 0.f;  // zero 3x2048 LN stats

    for (int k = t; k < 384; k += 256) {
        float f0 = hi[row_i * 768 + 2 * k] + b1[2 * k];
        float f1 = hi[row_i * 768 + 2 * k + 1] + b1[2 * k + 1];
        sHib[k] = f2h2v(f0, f1);
    }
    if (t < 128) sEw[t] = 0.f;

    const int wave = t >> 6, lane = t & 63;
    const int col = lane & 15, q = lane >> 4;
    const int hj_j = t >> 1;
    const int c0 = (t & 1) * 2;               // chunk pair {0,1} or {2,3}
    const int swz = (hj_j >> 1) & 3;
    const unsigned short* hjrow = hjh + (b * 128 + hj_j) * 768 + c0 * 8;
    const half2v z2 = {(_Float16)0.f, (_Float16)0.f};

    floatx4 acc[8][6];
    #pragma unroll
    for (int mt = 0; mt < 8; ++mt)
        #pragma unroll
        for (int nt = 0; nt < 6; ++nt) acc[mt][nt] = (floatx4){0.f, 0.f, 0.f, 0.f};

    // prologue: DMA W(0) -> sW[0]; form H(0)
    #pragma unroll
    for (int c = 0; c < 6; ++c) {
        int tile = wave * 6 + c;
        gload16(w2p + tile * 512 + lane * 8, &sW[0][tile * 512]);
    }
    {
        union { uint4 u; half2v h[4]; } a0, a1;
        a0.u = *(const uint4*)(hjrow);
        a1.u = *(const uint4*)(hjrow + 8);
        const half2v* hib = &sHib[c0 * 4];
        #pragma unroll
        for (int e = 0; e < 4; ++e) {
            a0.h[e] = __builtin_elementwise_max(a0.h[e] + hib[e], z2);
            a1.h[e] = __builtin_elementwise_max(a1.h[e] + hib[e + 4], z2);
        }
        *(uint4*)&sH[hj_j * 32 + ((c0 ^ swz) * 8)] = a0.u;
        *(uint4*)&sH[hj_j * 32 + (((c0 + 1) ^ swz) * 8)] = a1.u;
    }
    __syncthreads();

    for (int step = 0; step < 24; ++step) {
        const int p = step & 1;
        // DMA W(step+1) into other buffer (a full MFMA phase before its drain)
        if (step < 23) {
            #pragma unroll
            for (int c = 0; c < 6; ++c) {
                int tile = wave * 6 + c;
                gload16(w2p + (step + 1) * 12288 + tile * 512 + lane * 8,
                        &sW[p ^ 1][tile * 512]);
            }
        }
        // prefetch hj(step+1) to regs
        uint4 f0, f1;
        if (step < 23) {
            f0 = *(const uint4*)(hjrow + (step + 1) * 32);
            f1 = *(const uint4*)(hjrow + (step + 1) * 32 + 8);
        }
        // MFMA on sH (current) x sW[p]
        half8 aF[8];
        #pragma unroll
        for (int mt = 0; mt < 8; ++mt) {
            int j = mt * 16 + col;
            aF[mt] = *(const half8*)&sH[j * 32 + ((q ^ ((j >> 1) & 3)) * 8)];
        }
        #pragma unroll
        for (int nt = 0; nt < 6; ++nt) {
            half8 bF = *(const half8*)&sW[p][(wave * 6 + nt) * 512 + lane * 8];
            #pragma unroll
            for (int mt = 0; mt < 8; ++mt)
                acc[mt][nt] = mfma16(aF[mt], bF, acc[mt][nt]);
        }
        __syncthreads();   // all reads of sH done; drains DMA(step+1) (landed)
        if (step < 23) {   // form H(step+1)
            union { uint4 u; half2v h[4]; } a0, a1;
            a0.u = f0; a1.u = f1;
            const half2v* hib = &sHib[(step + 1) * 16 + c0 * 4];
            #pragma unroll
            for (int e = 0; e < 4; ++e) {
                a0.h[e] = __builtin_elementwise_max(a0.h[e] + hib[e], z2);
                a1.h[e] = __builtin_elementwise_max(a1.h[e] + hib[e + 4], z2);
            }
            *(uint4*)&sH[hj_j * 32 + ((c0 ^ swz) * 8)] = a0.u;
            *(uint4*)&sH[hj_j * 32 + (((c0 + 1) ^ swz) * 8)] = a1.u;
        }
        __syncthreads();
    }

    // epilogue: ew_partial[j] += sum_n relu(U+b2)*w3[n]  (wave's 96-col slice)
    #pragma unroll
    for (int mt = 0; mt < 8; ++mt) {
        float s0 = 0.f, s1 = 0.f, s2 = 0.f, s3 = 0.f;
        #pragma unroll
        for (int nt = 0; nt < 6; ++nt) {
            int n = wave * 96 + nt * 16 + col;
            float w3n = w3[n], b2n = b2[n];
            s0 += fmaxf(acc[mt][nt][0] + b2n, 0.f) * w3n;
            s1 += fmaxf(acc[mt][nt][1] + b2n, 0.f) * w3n;
            s2 += fmaxf(acc[mt][nt][2] + b2n, 0.f) * w3n;
            s3 += fmaxf(acc[mt][nt][3] + b2n, 0.f) * w3n;
        }
        #pragma unroll
        for (int off = 1; off < 16; off <<= 1) {
            s0 += __shfl_xor(s0, off); s1 += __shfl_xor(s1, off);
            s2 += __shfl_xor(s2, off); s3 += __shfl_xor(s3, off);
        }
        if (col == 0) {
            int r = mt * 16 + q * 4;
            atomicAdd(&sEw[r + 0], s0); atomicAdd(&sEw[r + 1], s1);
            atomicAdd(&sEw[r + 2], s2); atomicAdd(&sEw[r + 3], s3);
        }
    }
    __syncthreads();
    // sigmoid -> adj*ew + I -> softmax over j
    float logit = -1e30f;
    if (t < 128) {
        float p = sEw[t] + b3[0];
        float ew = 1.f / (1.f + expf(-p));
        logit = adj[row_i * 128 + t] * ew + (t == i ? 1.f : 0.f);
    }
    float mx = logit;
    #pragma unroll
    for (int off = 1; off < 64; off <<= 1) mx = fmaxf(mx, __shfl_xor(mx, off));
    if (lane == 0 && wave < 2) sRed[wave] = mx;
    __syncthreads();
    mx = fmaxf(sRed[0], sRed[1]);
    float e = (t < 128) ? expf(logit - mx) : 0.f;
    float sm = e;
    #pragma unroll
    for (int off = 1; off < 64; off <<= 1) sm += __shfl_xor(sm, off);
    if (lane == 0 && wave < 2) sRed[2 + wave] = sm;
    __syncthreads();
    float tot = sRed[2] + sRed[3];
    if (t < 128) ah[row_i * 128 + t] = f2h(e / tot);
}

// ---- GCN layer kernel: ax(_LN) = (a+I)@[LN(y_prev)|x]; Y = ax@gw; relu+stats -
// grid (4 nq, 8 t, 8 b) x 256.  LN fused via A-scaling when gS_in != null.
__global__ __launch_bounds__(256) void gcnA_kernel(
    const unsigned short* __restrict__ ah, const unsigned short* __restrict__ xsrc,
    const unsigned short* __restrict__ yprevT,
    const float* __restrict__ gS_in, const float* __restrict__ gQ_in,
    const float* __restrict__ lng_p, const float* __restrict__ lnb_p,
    const unsigned short* __restrict__ gwp_l, const float* __restrict__ gb_l,
    unsigned short* __restrict__ yT_out, unsigned short* __restrict__ yb_out,
    float* __restrict__ gS_out, float* __restrict__ gQ_out) {
    __shared__ __align__(16) unsigned short sBuf[16 * 776];
    __shared__ float sMu[128], sRstd[128];
    const int nq = blockIdx.x, t0 = blockIdx.y * 16, b = blockIdx.z;
    const int t = threadIdx.x, wave = t >> 6, lane = t & 63;
    const int col = lane & 15, q = lane >> 4;
    const bool hasLN = (gS_in != nullptr);

    if (hasLN) {
        if (t < 128) {
            int row = b * 128 + t;
            float mu = gS_in[row] * (1.f / 768.f);
            float va = gQ_in[row] * (1.f / 768.f) - mu * mu;
            sMu[t] = mu; sRstd[t] = rsqrtf(va + 1e-5f);
        }
        __syncthreads();
    }

    // ---- phase 1 ----
    floatx4 acc1[12];
    #pragma unroll
    for (int nt = 0; nt < 12; ++nt) acc1[nt] = (floatx4){0.f, 0.f, 0.f, 0.f};
    float cp = 0.f;
    {
        const unsigned short* arow = ah + (b * 128 + t0 + col) * 128;
        const int token = t0 + col;
        #pragma unroll
        for (int kc = 0; kc < 4; ++kc) {
            half8 aF1 = *(const half8*)&arow[kc * 32 + q * 8];
            const int kb = kc * 32 + q * 8;
            if (!hasLN) {
                if (token >= kb && token < kb + 8)
                    aF1[token - kb] = (_Float16)((float)aF1[token - kb] + 1.0f);
                #pragma unroll
                for (int nt = 0; nt < 12; ++nt) {
                    half8 bF = *(const half8*)&xsrc[((b * 4 + kc) * 48 + wave * 12 + nt) * 512 + lane * 8];
                    acc1[nt] = mfma16(aF1, bF, acc1[nt]);
                }
            } else {
                #pragma unroll
                for (int e = 0; e < 8; ++e) {
                    int tk = kb + e;
                    float av = (float)aF1[e] + (tk == token ? 1.f : 0.f);
                    float as = av * sRstd[tk];
                    cp += as * sMu[tk];
                    aF1[e] = (_Float16)as;
                }
                #pragma unroll
                for (int nt = 0; nt < 12; ++nt) {
                    int n = wave * 192 + nt * 16 + col;
                    half8 bF = *(const half8*)&yprevT[(b * 768 + n) * 128 + kc * 32 + q * 8];
                    acc1[nt] = mfma16(aF1, bF, acc1[nt]);
                }
            }
        }
    }
    float cR[4] = {0.f, 0.f, 0.f, 0.f};
    if (hasLN) {
        cp += __shfl_xor(cp, 16); cp += __shfl_xor(cp, 32);
        #pragma unroll
        for (int r = 0; r < 4; ++r) cR[r] = __shfl(cp, q * 4 + r);
    }
    // ax(_LN) -> sBuf in A-layout (row-major, stride 776)
    #pragma unroll
    for (int nt = 0; nt < 12; ++nt) {
        int n = wave * 192 + nt * 16 + col;
        float lg = hasLN ? lng_p[n] : 0.f;
        float lb = hasLN ? lnb_p[n] : 0.f;
        #pragma unroll
        for (int r = 0; r < 4; ++r) {
            float v = acc1[nt][r];
            if (hasLN) v = lg * (v - cR[r]) + 2.f * lb;
            sBuf[(q * 4 + r) * 776 + n] = f2h(v);
        }
    }
    __syncthreads();

    // ---- phase 2: Y quarter nq ----
    floatx4 acc2[3];
    #pragma unroll
    for (int nt = 0; nt < 3; ++nt) acc2[nt] = (floatx4){0.f, 0.f, 0.f, 0.f};
    for (int s = 0; s < 24; ++s) {
        half8 aF = *(const half8*)&sBuf[col * 776 + s * 32 + q * 8];
        #pragma unroll
        for (int nt = 0; nt < 3; ++nt) {
            int ntg = nq * 12 + wave * 3 + nt;
            half8 bF = *(const half8*)&gwp_l[(s * 48 + ntg) * 512 + lane * 8];
            acc2[nt] = mfma16(aF, bF, acc2[nt]);
        }
    }

    // epilogue: v = relu(Y*0.5 + gb); store yT (packed) or yb (row-major); stats
    float ps[4] = {0.f, 0.f, 0.f, 0.f}, pq[4] = {0.f, 0.f, 0.f, 0.f};
    #pragma unroll
    for (int nt = 0; nt < 3; ++nt) {
        int n = nq * 192 + wave * 48 + nt * 16 + col;
        float g = gb_l[n];
        float v[4];
        #pragma unroll
        for (int r = 0; r < 4; ++r) {
            v[r] = fmaxf(acc2[nt][r] * 0.5f + g, 0.f);
            ps[r] += v[r]; pq[r] += v[r] * v[r];
        }
        if (yT_out) {
            union { half2v h[2]; uint2 u; } pk;
            pk.h[0] = f2h2v(v[0], v[1]);
            pk.h[1] = f2h2v(v[2], v[3]);
            *(uint2*)&yT_out[(b * 768 + n) * 128 + t0 + q * 4] = pk.u;
        } else {
            #pragma unroll
            for (int r = 0; r < 4; ++r)
                yb_out[(b * 128 + t0 + q * 4 + r) * 768 + n] = f2h(v[r]);
        }
    }
    #pragma unroll
    for (int off = 1; off < 16; off <<= 1) {
        #pragma unroll
        for (int r = 0; r < 4; ++r) {
            ps[r] += __shfl_xor(ps[r], off);
            pq[r] += __shfl_xor(pq[r], off);
        }
    }
    if (col == 0) {
        #pragma unroll
        for (int r = 0; r < 4; ++r) {
            int row = b * 128 + t0 + q * 4 + r;
            atomicAdd(&gS_out[row], ps[r]);
            atomicAdd(&gQ_out[row], pq[r]);
        }
    }
}

// ---- final LN: normalize y3 and write fp32 output --------------------------
__global__ __launch_bounds__(128) void gcnBfin_kernel(
    const unsigned short* __restrict__ yb, const float* __restrict__ gS,
    const float* __restrict__ gQ, const float* __restrict__ lng_l,
    const float* __restrict__ lnb_l, float* __restrict__ outf) {
    const int row = blockIdx.x, t = threadIdx.x;
    const float mu = gS[row] * (1.f / 768.f);
    const float va = gQ[row] * (1.f / 768.f) - mu * mu;
    const float rstd = rsqrtf(va + 1e-5f);
    if (t < 96) {
        union { uint4 u; unsigned short s[8]; } v;
        v.u = *(const uint4*)&yb[row * 768 + t * 8];
        #pragma unroll
        for (int e = 0; e < 8; ++e) {
            int d = t * 8 + e;
            outf[row * 768 + d] = (h2f(v.s[e]) - mu) * rstd * lng_l[d] + lnb_l[d];
        }
    }
}

// ------------------------------- launch -------------------------------------
extern "C" void kernel_launch(void* const* d_in, const int* in_sizes, int n_in,
                              void* d_out, int out_size, void* d_ws, size_t ws_size,
                              hipStream_t stream) {
    const float* adj = (const float*)d_in[0];
    const float* x   = (const float*)d_in[1];
    const float* w1  = (const float*)d_in[2];
    const float* b1  = (const float*)d_in[3];
    const float* w2  = (const float*)d_in[4];
    const float* b2  = (const float*)d_in[5];
    const float* w3  = (const float*)d_in[6];
    const float* b3  = (const float*)d_in[7];
    const float* gw  = (const float*)d_in[8];
    const float* gb  = (const float*)d_in[9];
    const float* lng = (const float*)d_in[10];
    const float* lnb = (const float*)d_in[11];
    float* outp = (float*)d_out;  // 786432 out + 1024 mask

    char* ws = (char*)d_ws;
    unsigned short* w1t = (unsigned short*)(ws + 0);         // 1536x768 f16 [n][k]
    unsigned short* w2p = (unsigned short*)(ws + 2359296);   // 24x24x512 frag
    unsigned short* gwp = (unsigned short*)(ws + 2949120);   // 3x(24x48x512) frag
    unsigned short* xh  = (unsigned short*)(ws + 6488064);   // 1024x768 f16
    float*          hi  = (float*)        (ws + 8060928);    // 1024x768 fp32
    unsigned short* hjh = (unsigned short*)(ws + 11206656);  // 1024x768 f16
    unsigned short* ah  = (unsigned short*)(ws + 12779520);  // 8x128x128 f16
    unsigned short* xpk = (unsigned short*)(ws + 13041664);  // 8x4x48x512 frag
    unsigned short* yb  = (unsigned short*)(ws + 14614528);  // 1024x768 f16
    // aliases over dead regions:
    float* stats = (float*)(ws + 6488064);                   // 3x(gS|gQ), over xh
    unsigned short* y1T = (unsigned short*)(ws + 0);         // over w1t
    unsigned short* y2T = (unsigned short*)(ws + 8060928);   // over hi

    prep_kernel<<<dim3(24, 24, 15), dim3(32, 8), 0, stream>>>(
        x, w1, w2, gw, w1t, w2p, gwp, xh, xpk, outp + 786432);
    gemm128_kernel<<<dim3(12, 8), 256, 0, stream>>>(xh, w1t, hi, hjh);
    edge_kernel<<<1024, 256, 0, stream>>>(hi, hjh, b1, w2p, b2, w3, b3, adj, ah, stats);

    float* S1 = stats,        *Q1 = stats + 1024;
    float* S2 = stats + 2048, *Q2 = stats + 3072;
    float* S3 = stats + 4096, *Q3 = stats + 5120;

    // layer 1: src = x (packed), no LN; out y1T + stats1
    gcnA_kernel<<<dim3(4, 8, 8), 256, 0, stream>>>(
        ah, xpk, nullptr, nullptr, nullptr, nullptr, nullptr,
        gwp, gb, y1T, nullptr, S1, Q1);
    // layer 2: src = LN(y1) fused; out y2T + stats2
    gcnA_kernel<<<dim3(4, 8, 8), 256, 0, stream>>>(
        ah, nullptr, y1T, S1, Q1, lng, lnb,
        gwp + 589824, gb + 768, y2T, nullptr, S2, Q2);
    // layer 3: src = LN(y2) fused; out yb row-major + stats3
    gcnA_kernel<<<dim3(4, 8, 8), 256, 0, stream>>>(
        ah, nullptr, y2T, S2, Q2, lng + 768, lnb + 768,
        gwp + 1179648, gb + 1536, nullptr, yb, S3, Q3);
    // final LN -> fp32 output
    gcnBfin_kernel<<<1024, 128, 0, stream>>>(yb, S3, Q3, lng + 1536, lnb + 1536, outp);
}

// Round 10
// 268.273 us; speedup vs baseline: 1.0252x; 1.0252x over previous
//
#include <hip/hip_runtime.h>
#include <hip/hip_fp16.h>
#include <stdint.h>

// AdaptiveGCN: B=8, L=128, D=768.  All-f16 MFMA pipeline.
// Algebra: denom==2.0 exactly; mask==all-False; (ax+out)@gw+2gb == ((a+I)@out)@gw+2gb;
// concat-linear splits into hi = x@w1[:D], hj = x@w1[D:].
// R10: R9 + the missing __syncthreads() after sHib fill (R8/R9 prologue race fix).
//     Edge: N split 4 ways (grid 1024x4), acc[4][3], launch_bounds(256,4) ->
//     16 waves/CU; dbuf H + dbuf W, one barrier/step; ew via global atomics.

typedef __attribute__((ext_vector_type(8))) _Float16 half8;
typedef __attribute__((ext_vector_type(2))) _Float16 half2v;
typedef __attribute__((ext_vector_type(2))) __fp16 fp16x2;   // cvt_pkrtz ret type
typedef __attribute__((ext_vector_type(4))) float floatx4;

__device__ __forceinline__ unsigned short f2h(float f) {
    union { fp16x2 p; unsigned short s[2]; } v;
    v.p = __builtin_amdgcn_cvt_pkrtz(f, f);
    return v.s[0];
}
__device__ __forceinline__ half2v f2h2v(float a, float b) {
    union { fp16x2 p; half2v h; } v;
    v.p = __builtin_amdgcn_cvt_pkrtz(a, b);
    return v.h;
}
__device__ __forceinline__ float h2f(unsigned short u) {
    union { unsigned short u; _Float16 h; } c; c.u = u;
    return (float)c.h;
}
__device__ __forceinline__ floatx4 mfma16(half8 a, half8 b, floatx4 c) {
    return __builtin_amdgcn_mfma_f32_16x16x32_f16(a, b, c, 0, 0, 0);
}
__device__ __forceinline__ void gload16(const void* g, void* lds) {
    __builtin_amdgcn_global_load_lds(
        (const __attribute__((address_space(1))) void*)g,
        (__attribute__((address_space(3))) void*)lds, 16, 0, 0);
}

// B-fragment pack: tile(s = k-chunk32, ntile = n-group16) = 512 shorts;
// element (n_local, k_local) at lane=(k_local>>3)*16+n_local, e=k_local&7.

// ---------------- prep: all weight conversions / packings -------------------
__global__ void prep_kernel(const float* __restrict__ x, const float* __restrict__ w1,
                            const float* __restrict__ w2, const float* __restrict__ gw,
                            unsigned short* __restrict__ w1t,
                            unsigned short* __restrict__ w2p,
                            unsigned short* __restrict__ gwp,
                            unsigned short* __restrict__ xh,
                            unsigned short* __restrict__ xpk,
                            float* __restrict__ ewg,
                            float* __restrict__ maskout) {
    const int z = blockIdx.z;
    const int tx = threadIdx.x, ty = threadIdx.y;  // 32 x 8
    const int t = ty * 32 + tx;

    if (z == 5) {  // w2 (768x384 fp32 [k][n]) -> w2p frag tiles (s*24+ntg)*512
        const int s = blockIdx.x, ntg = blockIdx.y;  // both 0..23
        const int lane = t >> 2, e0 = (t & 3) * 2;
        const int n = ntg * 16 + (lane & 15);
        const int kbase = s * 32 + (lane >> 4) * 8;
        unsigned short* dst = w2p + (s * 24 + ntg) * 512 + lane * 8 + e0;
        dst[0] = f2h(w2[(kbase + e0) * 384 + n]);
        dst[1] = f2h(w2[(kbase + e0 + 1) * 384 + n]);
        return;
    }
    if (z == 6) {  // x fp32 -> f16 row-major; zero ewg + mask
        int gid = (blockIdx.y * 24 + blockIdx.x) * 256 + t;
        for (int i = gid; i < 786432; i += 24 * 24 * 256) xh[i] = f2h(x[i]);
        if (gid < 131072) ewg[gid] = 0.f;
        if (gid < 1024) maskout[gid] = 0.f;
        return;
    }
    if (z < 2) {  // w1 halves: transpose 768x768 fp32 -> f16 [n][k]
        const float* src = w1 + z * 589824;
        unsigned short* dst = w1t + z * 589824;
        const int c0 = blockIdx.x * 32, r0 = blockIdx.y * 32;
        __shared__ float tile[32][33];
        #pragma unroll
        for (int yy = ty; yy < 32; yy += 8)
            tile[yy][tx] = src[(r0 + yy) * 768 + (c0 + tx)];
        __syncthreads();
        #pragma unroll
        for (int yy = ty; yy < 32; yy += 8)
            dst[(c0 + yy) * 768 + (r0 + tx)] = f2h(tile[tx][yy]);
        return;
    }
    // frag-pack paths: z=2..4 -> gw layer (768x768 [k][n]); z=7..14 -> x batch
    const float* src; unsigned short* dstb; long tprefix; int rows;
    if (z <= 4) {
        int li = z - 2;
        src = gw + li * 589824; dstb = gwp + (long)li * 589824;
        tprefix = 0; rows = 768;
    } else {
        int bz = z - 7;
        src = x + bz * 98304; dstb = xpk;
        tprefix = (long)bz * 4; rows = 128;
    }
    const int c0 = blockIdx.x * 32, r0 = blockIdx.y * 32;
    if (r0 >= rows) return;
    __shared__ float tile[32][33];
    #pragma unroll
    for (int yy = ty; yy < 32; yy += 8)
        tile[yy][tx] = src[(r0 + yy) * 768 + (c0 + tx)];
    __syncthreads();
    if (t < 128) {
        const int n_off = t & 31, kg = t >> 5;
        const int s = r0 >> 5;
        long tileIdx = (tprefix + s) * 48 + (c0 >> 4) + (n_off >> 4);
        unsigned short* dst = dstb + tileIdx * 512 + (kg * 16 + (n_off & 15)) * 8;
        union { uint4 u; unsigned short s[8]; } pk;
        #pragma unroll
        for (int e = 0; e < 8; ++e) pk.s[e] = f2h(tile[kg * 8 + e][n_off]);
        *(uint4*)dst = pk.u;
    }
}

// --------- 128x128-tile f16 GEMM: hi|hj = x @ [w1_top|w1_bot]^T -------------
__global__ __launch_bounds__(256) void gemm128_kernel(
    const unsigned short* __restrict__ A, const unsigned short* __restrict__ Bm,
    float* __restrict__ hi, unsigned short* __restrict__ hjh) {
    __shared__ __align__(16) unsigned short sA[128 * 32];
    __shared__ __align__(16) unsigned short sB[128 * 32];
    const int n0 = blockIdx.x * 128, m0 = blockIdx.y * 128;
    const int t = threadIdx.x, wave = t >> 6, lane = t & 63;
    const int wm = wave >> 1, wn = wave & 1, col = lane & 15, q = lane >> 4;

    floatx4 acc[4][4];
    #pragma unroll
    for (int mt = 0; mt < 4; ++mt)
        #pragma unroll
        for (int nt = 0; nt < 4; ++nt) acc[mt][nt] = (floatx4){0.f, 0.f, 0.f, 0.f};

    for (int k0 = 0; k0 < 768; k0 += 32) {
        #pragma unroll
        for (int c = 0; c < 2; ++c) {
            int cid = (wave * 2 + c) * 64 + lane;
            int rw = cid >> 2;
            int half = (cid & 3) ^ ((rw >> 1) & 3);
            gload16(A + (m0 + rw) * 768 + k0 + half * 8, (char*)sA + (wave * 2 + c) * 1024);
            gload16(Bm + (n0 + rw) * 768 + k0 + half * 8, (char*)sB + (wave * 2 + c) * 1024);
        }
        __syncthreads();
        half8 aF[4], bF[4];
        #pragma unroll
        for (int mt = 0; mt < 4; ++mt) {
            int r = wm * 64 + mt * 16 + col;
            aF[mt] = *(const half8*)&sA[r * 32 + (q ^ ((r >> 1) & 3)) * 8];
        }
        #pragma unroll
        for (int nt = 0; nt < 4; ++nt) {
            int r = wn * 64 + nt * 16 + col;
            bF[nt] = *(const half8*)&sB[r * 32 + (q ^ ((r >> 1) & 3)) * 8];
        }
        #pragma unroll
        for (int mt = 0; mt < 4; ++mt)
            #pragma unroll
            for (int nt = 0; nt < 4; ++nt)
                acc[mt][nt] = mfma16(aF[mt], bF[nt], acc[mt][nt]);
        __syncthreads();
    }
    #pragma unroll
    for (int mt = 0; mt < 4; ++mt)
        #pragma unroll
        for (int nt = 0; nt < 4; ++nt) {
            int mg = m0 + wm * 64 + mt * 16 + q * 4;
            int ng = n0 + wn * 64 + nt * 16 + col;
            if (ng < 768) {
                #pragma unroll
                for (int r = 0; r < 4; ++r) hi[(mg + r) * 768 + ng] = acc[mt][nt][r];
            } else {
                #pragma unroll
                for (int r = 0; r < 4; ++r) hjh[(mg + r) * 768 + (ng - 768)] = f2h(acc[mt][nt][r]);
            }
        }
}

// ------------- edge kernel: block = (row_i, 96-col chunk nc) -----------------
// 256 thr = 4 waves, wave tile 2x2: wm -> 64 rows, wn -> 48 cols. acc[4][3].
// dbuf H + dbuf W, single barrier per step. ew partial -> global atomics.
__global__ __launch_bounds__(256, 4) void edge_kernel(
    const float* __restrict__ hi, const unsigned short* __restrict__ hjh,
    const float* __restrict__ b1, const unsigned short* __restrict__ w2p,
    const float* __restrict__ b2, const float* __restrict__ w3,
    float* __restrict__ ewg, float* __restrict__ statsAll) {
    __shared__ __align__(16) unsigned short sW[2][6 * 512];   // 12KB
    __shared__ __align__(16) unsigned short sH[2][128 * 32];  // 16KB
    __shared__ __align__(16) half2v sHib[384];
    __shared__ float sEw[128];

    const int t = threadIdx.x;
    const int row_i = blockIdx.x, nc = blockIdx.y;
    const int b = row_i >> 7;

    if (row_i < 24 && nc == 0) statsAll[row_i * 256 + t] = 0.f;  // zero 3x2048 LN stats

    for (int k = t; k < 384; k += 256) {
        float f0 = hi[row_i * 768 + 2 * k] + b1[2 * k];
        float f1 = hi[row_i * 768 + 2 * k + 1] + b1[2 * k + 1];
        sHib[k] = f2h2v(f0, f1);
    }
    if (t < 128) sEw[t] = 0.f;
    __syncthreads();  // R10 FIX: sHib must be visible before prologue H(0) formation

    const int wave = t >> 6, lane = t & 63;
    const int col = lane & 15, q = lane >> 4;
    const int wm = wave >> 1, wn = wave & 1;
    const int hj_j = t >> 1, c0 = (t & 1) * 2, swz = (hj_j >> 1) & 3;
    const unsigned short* hjrow = hjh + (b * 128 + hj_j) * 768 + c0 * 8;
    const half2v z2 = {(_Float16)0.f, (_Float16)0.f};

    floatx4 acc[4][3];
    #pragma unroll
    for (int mt = 0; mt < 4; ++mt)
        #pragma unroll
        for (int nt = 0; nt < 3; ++nt) acc[mt][nt] = (floatx4){0.f, 0.f, 0.f, 0.f};

    // prologue: DMA W(0); form H(0); prefetch hj(1)
    {
        int tile = wave * 2;
        if (tile < 6) {
            gload16(w2p + (nc * 6 + tile) * 512 + lane * 8, &sW[0][tile * 512]);
            gload16(w2p + (nc * 6 + tile + 1) * 512 + lane * 8, &sW[0][(tile + 1) * 512]);
        }
    }
    uint4 g0 = *(const uint4*)(hjrow);
    uint4 g1 = *(const uint4*)(hjrow + 8);
    {
        union { uint4 u; half2v h[4]; } a0, a1;
        a0.u = g0; a1.u = g1;
        const half2v* hib = &sHib[c0 * 4];
        #pragma unroll
        for (int e = 0; e < 4; ++e) {
            a0.h[e] = __builtin_elementwise_max(a0.h[e] + hib[e], z2);
            a1.h[e] = __builtin_elementwise_max(a1.h[e] + hib[e + 4], z2);
        }
        *(uint4*)&sH[0][hj_j * 32 + ((c0 ^ swz) * 8)] = a0.u;
        *(uint4*)&sH[0][hj_j * 32 + (((c0 + 1) ^ swz) * 8)] = a1.u;
    }
    g0 = *(const uint4*)(hjrow + 32);
    g1 = *(const uint4*)(hjrow + 32 + 8);
    __syncthreads();

    for (int step = 0; step < 24; ++step) {
        const int p = step & 1;
        if (step < 23) {
            // DMA W(step+1) into other buffer
            int tile = wave * 2;
            if (tile < 6) {
                gload16(w2p + ((step + 1) * 24 + nc * 6 + tile) * 512 + lane * 8,
                        &sW[p ^ 1][tile * 512]);
                gload16(w2p + ((step + 1) * 24 + nc * 6 + tile + 1) * 512 + lane * 8,
                        &sW[p ^ 1][(tile + 1) * 512]);
            }
            // form H(step+1) into other buffer (from regs loaded last step)
            union { uint4 u; half2v h[4]; } a0, a1;
            a0.u = g0; a1.u = g1;
            const half2v* hib = &sHib[(step + 1) * 16 + c0 * 4];
            #pragma unroll
            for (int e = 0; e < 4; ++e) {
                a0.h[e] = __builtin_elementwise_max(a0.h[e] + hib[e], z2);
                a1.h[e] = __builtin_elementwise_max(a1.h[e] + hib[e + 4], z2);
            }
            *(uint4*)&sH[p ^ 1][hj_j * 32 + ((c0 ^ swz) * 8)] = a0.u;
            *(uint4*)&sH[p ^ 1][hj_j * 32 + (((c0 + 1) ^ swz) * 8)] = a1.u;
            if (step < 22) {  // prefetch hj(step+2)
                g0 = *(const uint4*)(hjrow + (step + 2) * 32);
                g1 = *(const uint4*)(hjrow + (step + 2) * 32 + 8);
            }
        }
        // MFMA on current buffers
        half8 aF[4];
        #pragma unroll
        for (int mt = 0; mt < 4; ++mt) {
            int j = wm * 64 + mt * 16 + col;
            aF[mt] = *(const half8*)&sH[p][j * 32 + ((q ^ ((j >> 1) & 3)) * 8)];
        }
        #pragma unroll
        for (int nt = 0; nt < 3; ++nt) {
            half8 bF = *(const half8*)&sW[p][(wn * 3 + nt) * 512 + lane * 8];
            #pragma unroll
            for (int mt = 0; mt < 4; ++mt)
                acc[mt][nt] = mfma16(aF[mt], bF, acc[mt][nt]);
        }
        __syncthreads();
    }

    // epilogue: ew_partial[j] += sum_n relu(U+b2)*w3[n]  (this block's 96 cols)
    #pragma unroll
    for (int mt = 0; mt < 4; ++mt) {
        float s0 = 0.f, s1 = 0.f, s2 = 0.f, s3 = 0.f;
        #pragma unroll
        for (int nt = 0; nt < 3; ++nt) {
            int n = nc * 96 + wn * 48 + nt * 16 + col;
            float w3n = w3[n], b2n = b2[n];
            s0 += fmaxf(acc[mt][nt][0] + b2n, 0.f) * w3n;
            s1 += fmaxf(acc[mt][nt][1] + b2n, 0.f) * w3n;
            s2 += fmaxf(acc[mt][nt][2] + b2n, 0.f) * w3n;
            s3 += fmaxf(acc[mt][nt][3] + b2n, 0.f) * w3n;
        }
        #pragma unroll
        for (int off = 1; off < 16; off <<= 1) {
            s0 += __shfl_xor(s0, off); s1 += __shfl_xor(s1, off);
            s2 += __shfl_xor(s2, off); s3 += __shfl_xor(s3, off);
        }
        if (col == 0) {
            int r = wm * 64 + mt * 16 + q * 4;
            atomicAdd(&sEw[r + 0], s0); atomicAdd(&sEw[r + 1], s1);
            atomicAdd(&sEw[r + 2], s2); atomicAdd(&sEw[r + 3], s3);
        }
    }
    __syncthreads();
    if (t < 128) atomicAdd(&ewg[row_i * 128 + t], sEw[t]);
}

// ---- softmax kernel: ew -> sigmoid -> adj*ew + I -> softmax -> ah (f16) ----
__global__ __launch_bounds__(128) void sm_kernel(
    const float* __restrict__ ewg, const float* __restrict__ b3,
    const float* __restrict__ adj, unsigned short* __restrict__ ah) {
    __shared__ float sRed[4];
    const int row = blockIdx.x, t = threadIdx.x;
    const int i = row & 127;
    const int wave = t >> 6, lane = t & 63;
    float p = ewg[row * 128 + t] + b3[0];
    float ew = 1.f / (1.f + expf(-p));
    float logit = adj[row * 128 + t] * ew + (t == i ? 1.f : 0.f);
    float mx = logit;
    #pragma unroll
    for (int off = 1; off < 64; off <<= 1) mx = fmaxf(mx, __shfl_xor(mx, off));
    if (lane == 0) sRed[wave] = mx;
    __syncthreads();
    mx = fmaxf(sRed[0], sRed[1]);
    float e = expf(logit - mx);
    float sm = e;
    #pragma unroll
    for (int off = 1; off < 64; off <<= 1) sm += __shfl_xor(sm, off);
    if (lane == 0) sRed[2 + wave] = sm;
    __syncthreads();
    float tot = sRed[2] + sRed[3];
    ah[row * 128 + t] = f2h(e / tot);
}

// ---- GCN kernelA: Y = ((a+I)@src)@gw, relu(.5Y+gb), atomic LN stats --------
__global__ __launch_bounds__(256) void gcnA_kernel(
    const unsigned short* __restrict__ ah, const unsigned short* __restrict__ srcpk,
    const unsigned short* __restrict__ gwp_l, const float* __restrict__ gb_l,
    unsigned short* __restrict__ yb, float* __restrict__ gS, float* __restrict__ gQ) {
    __shared__ __align__(16) unsigned short sBuf[16 * 776];
    const int nq = blockIdx.x, t0 = blockIdx.y * 16, b = blockIdx.z;
    const int t = threadIdx.x, wave = t >> 6, lane = t & 63;
    const int col = lane & 15, q = lane >> 4;

    {
        floatx4 acc1[12];
        #pragma unroll
        for (int nt = 0; nt < 12; ++nt) acc1[nt] = (floatx4){0.f, 0.f, 0.f, 0.f};
        const unsigned short* arow = ah + (b * 128 + t0 + col) * 128;
        const int token = t0 + col;
        #pragma unroll
        for (int kc = 0; kc < 4; ++kc) {
            half8 aF1 = *(const half8*)&arow[kc * 32 + q * 8];
            int kb = kc * 32 + q * 8;
            if (token >= kb && token < kb + 8)
                aF1[token - kb] = (_Float16)((float)aF1[token - kb] + 1.0f);
            #pragma unroll
            for (int nt = 0; nt < 12; ++nt) {
                half8 bF = *(const half8*)&srcpk[((b * 4 + kc) * 48 + wave * 12 + nt) * 512 + lane * 8];
                acc1[nt] = mfma16(aF1, bF, acc1[nt]);
            }
        }
        #pragma unroll
        for (int nt = 0; nt < 12; ++nt) {
            int n = wave * 192 + nt * 16 + col;
            #pragma unroll
            for (int r = 0; r < 4; ++r)
                sBuf[(q * 4 + r) * 776 + n] = f2h(acc1[nt][r]);
        }
    }
    __syncthreads();

    floatx4 acc2[3];
    #pragma unroll
    for (int nt = 0; nt < 3; ++nt) acc2[nt] = (floatx4){0.f, 0.f, 0.f, 0.f};
    for (int s = 0; s < 24; ++s) {
        half8 aF = *(const half8*)&sBuf[col * 776 + s * 32 + q * 8];
        #pragma unroll
        for (int nt = 0; nt < 3; ++nt) {
            int ntg = nq * 12 + wave * 3 + nt;
            half8 bF = *(const half8*)&gwp_l[(s * 48 + ntg) * 512 + lane * 8];
            acc2[nt] = mfma16(aF, bF, acc2[nt]);
        }
    }

    float ps[4] = {0.f, 0.f, 0.f, 0.f}, pq[4] = {0.f, 0.f, 0.f, 0.f};
    #pragma unroll
    for (int nt = 0; nt < 3; ++nt) {
        int n = nq * 192 + wave * 48 + nt * 16 + col;
        float g = gb_l[n];
        #pragma unroll
        for (int r = 0; r < 4; ++r) {
            float v = fmaxf(acc2[nt][r] * 0.5f + g, 0.f);
            ps[r] += v; pq[r] += v * v;
            yb[(b * 128 + t0 + q * 4 + r) * 768 + n] = f2h(v);
        }
    }
    #pragma unroll
    for (int off = 1; off < 16; off <<= 1) {
        #pragma unroll
        for (int r = 0; r < 4; ++r) {
            ps[r] += __shfl_xor(ps[r], off);
            pq[r] += __shfl_xor(pq[r], off);
        }
    }
    if (col == 0) {
        #pragma unroll
        for (int r = 0; r < 4; ++r) {
            int row = b * 128 + t0 + q * 4 + r;
            atomicAdd(&gS[row], ps[r]);
            atomicAdd(&gQ[row], pq[r]);
        }
    }
}

// ---- GCN kernelB: LayerNorm apply; pack next-layer input OR write fp32 out -
__global__ __launch_bounds__(128) void gcnB_kernel(
    const unsigned short* __restrict__ yb, float* __restrict__ gS,
    float* __restrict__ gQ, const float* __restrict__ lng_l,
    const float* __restrict__ lnb_l, unsigned short* __restrict__ spk,
    float* __restrict__ outf) {
    const int row = blockIdx.x, t = threadIdx.x;
    const float mu = gS[row] * (1.f / 768.f);
    const float va = gQ[row] * (1.f / 768.f) - mu * mu;  // biased var (jnp.var)
    const float rstd = rsqrtf(va + 1e-5f);
    if (t < 96) {
        union { uint4 u; unsigned short s[8]; } v;
        v.u = *(const uint4*)&yb[row * 768 + t * 8];
        if (outf) {
            #pragma unroll
            for (int e = 0; e < 8; ++e) {
                int d = t * 8 + e;
                outf[row * 768 + d] = (h2f(v.s[e]) - mu) * rstd * lng_l[d] + lnb_l[d];
            }
        } else {
            const int b = row >> 7, tok = row & 127;
            const int kc = tok >> 5, kl = tok & 31, kg = kl >> 3, e2 = kl & 7;
            #pragma unroll
            for (int e = 0; e < 8; ++e) {
                int d = t * 8 + e;
                float o = (h2f(v.s[e]) - mu) * rstd * lng_l[d] + lnb_l[d];
                spk[(((long)(b * 4 + kc) * 48 + (d >> 4)) * 512) +
                    (kg * 16 + (d & 15)) * 8 + e2] = f2h(o);
            }
        }
    }
    __syncthreads();
    if (t == 0) { gS[row] = 0.f; gQ[row] = 0.f; }  // self-zero for next layer
}

// ------------------------------- launch -------------------------------------
extern "C" void kernel_launch(void* const* d_in, const int* in_sizes, int n_in,
                              void* d_out, int out_size, void* d_ws, size_t ws_size,
                              hipStream_t stream) {
    const float* adj = (const float*)d_in[0];
    const float* x   = (const float*)d_in[1];
    const float* w1  = (const float*)d_in[2];
    const float* b1  = (const float*)d_in[3];
    const float* w2  = (const float*)d_in[4];
    const float* b2  = (const float*)d_in[5];
    const float* w3  = (const float*)d_in[6];
    const float* b3  = (const float*)d_in[7];
    const float* gw  = (const float*)d_in[8];
    const float* gb  = (const float*)d_in[9];
    const float* lng = (const float*)d_in[10];
    const float* lnb = (const float*)d_in[11];
    float* outp = (float*)d_out;  // 786432 out + 1024 mask

    char* ws = (char*)d_ws;
    unsigned short* w1t = (unsigned short*)(ws + 0);         // 1536x768 f16 [n][k]
    unsigned short* w2p = (unsigned short*)(ws + 2359296);   // 24x24x512 frag
    unsigned short* gwp = (unsigned short*)(ws + 2949120);   // 3x(24x48x512) frag
    unsigned short* xh  = (unsigned short*)(ws + 6488064);   // 1024x768 f16
    float*          hi  = (float*)        (ws + 8060928);    // 1024x768 fp32
    unsigned short* hjh = (unsigned short*)(ws + 11206656);  // 1024x768 f16
    unsigned short* ah  = (unsigned short*)(ws + 12779520);  // 8x128x128 f16
    unsigned short* xpk = (unsigned short*)(ws + 13041664);  // 8x4x48x512 frag
    unsigned short* yb  = (unsigned short*)(ws + 14614528);  // 1024x768 f16
    float*          ewg = (float*)        (ws + 16187392);   // 1024x128 f32
    // aliases over dead regions:
    float* stats = (float*)(ws + 6488064);                   // 3x(gS|gQ), over xh
    unsigned short* spk0 = (unsigned short*)(ws + 0);        // over w1t
    unsigned short* spk1 = (unsigned short*)(ws + 11206656); // over hjh

    prep_kernel<<<dim3(24, 24, 15), dim3(32, 8), 0, stream>>>(
        x, w1, w2, gw, w1t, w2p, gwp, xh, xpk, ewg, outp + 786432);
    gemm128_kernel<<<dim3(12, 8), 256, 0, stream>>>(xh, w1t, hi, hjh);
    edge_kernel<<<dim3(1024, 4), 256, 0, stream>>>(hi, hjh, b1, w2p, b2, w3, ewg, stats);
    sm_kernel<<<1024, 128, 0, stream>>>(ewg, b3, adj, ah);

    float* S1 = stats,        *Q1 = stats + 1024;
    float* S2 = stats + 2048, *Q2 = stats + 3072;
    float* S3 = stats + 4096, *Q3 = stats + 5120;

    const unsigned short* srcs[3] = { xpk, spk0, spk1 };
    unsigned short* dsts[3] = { spk0, spk1, nullptr };
    float* Ss[3] = { S1, S2, S3 }; float* Qs[3] = { Q1, Q2, Q3 };
    for (int li = 0; li < 3; ++li) {
        gcnA_kernel<<<dim3(4, 8, 8), 256, 0, stream>>>(
            ah, srcs[li], gwp + (long)li * 589824, gb + li * 768, yb, Ss[li], Qs[li]);
        gcnB_kernel<<<1024, 128, 0, stream>>>(
            yb, Ss[li], Qs[li], lng + li * 768, lnb + li * 768, dsts[li],
            (li == 2) ? outp : nullptr);
    }
}

// Round 11
// 246.470 us; speedup vs baseline: 1.1159x; 1.0885x over previous
//
#include <hip/hip_runtime.h>
#include <hip/hip_fp16.h>
#include <stdint.h>

// AdaptiveGCN: B=8, L=128, D=768.  All-f16 MFMA pipeline.
// Algebra: denom==2.0 exactly; mask==all-False; (ax+out)@gw+2gb == ((a+I)@out)@gw+2gb;
// concat-linear splits into hi = x@w1[:D], hj = x@w1[D:];
// LN fused into next layer's A: (a+I)@LN(y) = lng*((a'*rstd)@y - c) + 2*lnb.
// R11: edge retile: nc=2, wave 64x96 (acc[4][6]) -> 2.4 MFMA/KB LDS, 2x H redund;
//     launch_bounds(256,3); same race-free single-barrier dbuf skeleton as R10.
//     Tail: LN fusion retry (R8 0.125 was the race, proven), gcnA ph2 prefetch.

typedef __attribute__((ext_vector_type(8))) _Float16 half8;
typedef __attribute__((ext_vector_type(2))) _Float16 half2v;
typedef __attribute__((ext_vector_type(2))) __fp16 fp16x2;   // cvt_pkrtz ret type
typedef __attribute__((ext_vector_type(4))) float floatx4;

__device__ __forceinline__ unsigned short f2h(float f) {
    union { fp16x2 p; unsigned short s[2]; } v;
    v.p = __builtin_amdgcn_cvt_pkrtz(f, f);
    return v.s[0];
}
__device__ __forceinline__ half2v f2h2v(float a, float b) {
    union { fp16x2 p; half2v h; } v;
    v.p = __builtin_amdgcn_cvt_pkrtz(a, b);
    return v.h;
}
__device__ __forceinline__ float h2f(unsigned short u) {
    union { unsigned short u; _Float16 h; } c; c.u = u;
    return (float)c.h;
}
__device__ __forceinline__ floatx4 mfma16(half8 a, half8 b, floatx4 c) {
    return __builtin_amdgcn_mfma_f32_16x16x32_f16(a, b, c, 0, 0, 0);
}
__device__ __forceinline__ void gload16(const void* g, void* lds) {
    __builtin_amdgcn_global_load_lds(
        (const __attribute__((address_space(1))) void*)g,
        (__attribute__((address_space(3))) void*)lds, 16, 0, 0);
}

// B-fragment pack: tile(s = k-chunk32, ntile = n-group16) = 512 shorts;
// element (n_local, k_local) at lane=(k_local>>3)*16+n_local, e=k_local&7.

// ---------------- prep: all weight conversions / packings -------------------
__global__ void prep_kernel(const float* __restrict__ x, const float* __restrict__ w1,
                            const float* __restrict__ w2, const float* __restrict__ gw,
                            unsigned short* __restrict__ w1t,
                            unsigned short* __restrict__ w2p,
                            unsigned short* __restrict__ gwp,
                            unsigned short* __restrict__ xh,
                            unsigned short* __restrict__ xpk,
                            float* __restrict__ ewg,
                            float* __restrict__ maskout) {
    const int z = blockIdx.z;
    const int tx = threadIdx.x, ty = threadIdx.y;  // 32 x 8
    const int t = ty * 32 + tx;

    if (z == 5) {  // w2 (768x384 fp32 [k][n]) -> w2p frag tiles (s*24+ntg)*512
        const int s = blockIdx.x, ntg = blockIdx.y;  // both 0..23
        const int lane = t >> 2, e0 = (t & 3) * 2;
        const int n = ntg * 16 + (lane & 15);
        const int kbase = s * 32 + (lane >> 4) * 8;
        unsigned short* dst = w2p + (s * 24 + ntg) * 512 + lane * 8 + e0;
        dst[0] = f2h(w2[(kbase + e0) * 384 + n]);
        dst[1] = f2h(w2[(kbase + e0 + 1) * 384 + n]);
        return;
    }
    if (z == 6) {  // x fp32 -> f16 row-major; zero ewg + mask
        int gid = (blockIdx.y * 24 + blockIdx.x) * 256 + t;
        for (int i = gid; i < 786432; i += 24 * 24 * 256) xh[i] = f2h(x[i]);
        if (gid < 131072) ewg[gid] = 0.f;
        if (gid < 1024) maskout[gid] = 0.f;
        return;
    }
    if (z < 2) {  // w1 halves: transpose 768x768 fp32 -> f16 [n][k]
        const float* src = w1 + z * 589824;
        unsigned short* dst = w1t + z * 589824;
        const int c0 = blockIdx.x * 32, r0 = blockIdx.y * 32;
        __shared__ float tile[32][33];
        #pragma unroll
        for (int yy = ty; yy < 32; yy += 8)
            tile[yy][tx] = src[(r0 + yy) * 768 + (c0 + tx)];
        __syncthreads();
        #pragma unroll
        for (int yy = ty; yy < 32; yy += 8)
            dst[(c0 + yy) * 768 + (r0 + tx)] = f2h(tile[tx][yy]);
        return;
    }
    // frag-pack paths: z=2..4 -> gw layer (768x768 [k][n]); z=7..14 -> x batch
    const float* src; unsigned short* dstb; long tprefix; int rows;
    if (z <= 4) {
        int li = z - 2;
        src = gw + li * 589824; dstb = gwp + (long)li * 589824;
        tprefix = 0; rows = 768;
    } else {
        int bz = z - 7;
        src = x + bz * 98304; dstb = xpk;
        tprefix = (long)bz * 4; rows = 128;
    }
    const int c0 = blockIdx.x * 32, r0 = blockIdx.y * 32;
    if (r0 >= rows) return;
    __shared__ float tile[32][33];
    #pragma unroll
    for (int yy = ty; yy < 32; yy += 8)
        tile[yy][tx] = src[(r0 + yy) * 768 + (c0 + tx)];
    __syncthreads();
    if (t < 128) {
        const int n_off = t & 31, kg = t >> 5;
        const int s = r0 >> 5;
        long tileIdx = (tprefix + s) * 48 + (c0 >> 4) + (n_off >> 4);
        unsigned short* dst = dstb + tileIdx * 512 + (kg * 16 + (n_off & 15)) * 8;
        union { uint4 u; unsigned short s[8]; } pk;
        #pragma unroll
        for (int e = 0; e < 8; ++e) pk.s[e] = f2h(tile[kg * 8 + e][n_off]);
        *(uint4*)dst = pk.u;
    }
}

// --------- 128x128-tile f16 GEMM: hi|hj = x @ [w1_top|w1_bot]^T -------------
__global__ __launch_bounds__(256) void gemm128_kernel(
    const unsigned short* __restrict__ A, const unsigned short* __restrict__ Bm,
    float* __restrict__ hi, unsigned short* __restrict__ hjh) {
    __shared__ __align__(16) unsigned short sA[128 * 32];
    __shared__ __align__(16) unsigned short sB[128 * 32];
    const int n0 = blockIdx.x * 128, m0 = blockIdx.y * 128;
    const int t = threadIdx.x, wave = t >> 6, lane = t & 63;
    const int wm = wave >> 1, wn = wave & 1, col = lane & 15, q = lane >> 4;

    floatx4 acc[4][4];
    #pragma unroll
    for (int mt = 0; mt < 4; ++mt)
        #pragma unroll
        for (int nt = 0; nt < 4; ++nt) acc[mt][nt] = (floatx4){0.f, 0.f, 0.f, 0.f};

    for (int k0 = 0; k0 < 768; k0 += 32) {
        #pragma unroll
        for (int c = 0; c < 2; ++c) {
            int cid = (wave * 2 + c) * 64 + lane;
            int rw = cid >> 2;
            int half = (cid & 3) ^ ((rw >> 1) & 3);
            gload16(A + (m0 + rw) * 768 + k0 + half * 8, (char*)sA + (wave * 2 + c) * 1024);
            gload16(Bm + (n0 + rw) * 768 + k0 + half * 8, (char*)sB + (wave * 2 + c) * 1024);
        }
        __syncthreads();
        half8 aF[4], bF[4];
        #pragma unroll
        for (int mt = 0; mt < 4; ++mt) {
            int r = wm * 64 + mt * 16 + col;
            aF[mt] = *(const half8*)&sA[r * 32 + (q ^ ((r >> 1) & 3)) * 8];
        }
        #pragma unroll
        for (int nt = 0; nt < 4; ++nt) {
            int r = wn * 64 + nt * 16 + col;
            bF[nt] = *(const half8*)&sB[r * 32 + (q ^ ((r >> 1) & 3)) * 8];
        }
        #pragma unroll
        for (int mt = 0; mt < 4; ++mt)
            #pragma unroll
            for (int nt = 0; nt < 4; ++nt)
                acc[mt][nt] = mfma16(aF[mt], bF[nt], acc[mt][nt]);
        __syncthreads();
    }
    #pragma unroll
    for (int mt = 0; mt < 4; ++mt)
        #pragma unroll
        for (int nt = 0; nt < 4; ++nt) {
            int mg = m0 + wm * 64 + mt * 16 + q * 4;
            int ng = n0 + wn * 64 + nt * 16 + col;
            if (ng < 768) {
                #pragma unroll
                for (int r = 0; r < 4; ++r) hi[(mg + r) * 768 + ng] = acc[mt][nt][r];
            } else {
                #pragma unroll
                for (int r = 0; r < 4; ++r) hjh[(mg + r) * 768 + (ng - 768)] = f2h(acc[mt][nt][r]);
            }
        }
}

// ------------- edge kernel: block = (row_i, 192-col half nc) -----------------
// 256 thr = 4 waves, wave tile 2x2: wm -> 64 rows, wn -> 96 cols. acc[4][6].
// dbuf H + dbuf W, single barrier per step. ew partial -> global atomics.
__global__ __launch_bounds__(256, 3) void edge_kernel(
    const float* __restrict__ hi, const unsigned short* __restrict__ hjh,
    const float* __restrict__ b1, const unsigned short* __restrict__ w2p,
    const float* __restrict__ b2, const float* __restrict__ w3,
    float* __restrict__ ewg, float* __restrict__ statsAll) {
    __shared__ __align__(16) unsigned short sW[2][12 * 512];  // 24KB
    __shared__ __align__(16) unsigned short sH[2][128 * 32];  // 16KB
    __shared__ __align__(16) half2v sHib[384];
    __shared__ float sEw[128];

    const int t = threadIdx.x;
    const int row_i = blockIdx.x, nc = blockIdx.y;
    const int b = row_i >> 7;

    if (row_i < 24 && nc == 0) statsAll[row_i * 256 + t] = 0.f;  // zero 3x2048 LN stats

    for (int k = t; k < 384; k += 256) {
        float f0 = hi[row_i * 768 + 2 * k] + b1[2 * k];
        float f1 = hi[row_i * 768 + 2 * k + 1] + b1[2 * k + 1];
        sHib[k] = f2h2v(f0, f1);
    }
    if (t < 128) sEw[t] = 0.f;
    __syncthreads();  // sHib visible before prologue H(0) formation

    const int wave = t >> 6, lane = t & 63;
    const int col = lane & 15, q = lane >> 4;
    const int wm = wave >> 1, wn = wave & 1;
    const int hj_j = t >> 1, c0 = (t & 1) * 2, swz = (hj_j >> 1) & 3;
    const unsigned short* hjrow = hjh + (b * 128 + hj_j) * 768 + c0 * 8;
    const half2v z2 = {(_Float16)0.f, (_Float16)0.f};

    floatx4 acc[4][6];
    #pragma unroll
    for (int mt = 0; mt < 4; ++mt)
        #pragma unroll
        for (int nt = 0; nt < 6; ++nt) acc[mt][nt] = (floatx4){0.f, 0.f, 0.f, 0.f};

    // prologue: DMA W(0); form H(0); prefetch hj(1)
    #pragma unroll
    for (int c = 0; c < 3; ++c) {
        int tile = wave * 3 + c;
        gload16(w2p + (nc * 12 + tile) * 512 + lane * 8, &sW[0][tile * 512]);
    }
    uint4 g0 = *(const uint4*)(hjrow);
    uint4 g1 = *(const uint4*)(hjrow + 8);
    {
        union { uint4 u; half2v h[4]; } a0, a1;
        a0.u = g0; a1.u = g1;
        const half2v* hib = &sHib[c0 * 4];
        #pragma unroll
        for (int e = 0; e < 4; ++e) {
            a0.h[e] = __builtin_elementwise_max(a0.h[e] + hib[e], z2);
            a1.h[e] = __builtin_elementwise_max(a1.h[e] + hib[e + 4], z2);
        }
        *(uint4*)&sH[0][hj_j * 32 + ((c0 ^ swz) * 8)] = a0.u;
        *(uint4*)&sH[0][hj_j * 32 + (((c0 + 1) ^ swz) * 8)] = a1.u;
    }
    g0 = *(const uint4*)(hjrow + 32);
    g1 = *(const uint4*)(hjrow + 32 + 8);
    __syncthreads();

    for (int step = 0; step < 24; ++step) {
        const int p = step & 1;
        if (step < 23) {
            // DMA W(step+1) into other buffer
            #pragma unroll
            for (int c = 0; c < 3; ++c) {
                int tile = wave * 3 + c;
                gload16(w2p + ((step + 1) * 24 + nc * 12 + tile) * 512 + lane * 8,
                        &sW[p ^ 1][tile * 512]);
            }
            // form H(step+1) into other buffer (from regs loaded last step)
            union { uint4 u; half2v h[4]; } a0, a1;
            a0.u = g0; a1.u = g1;
            const half2v* hib = &sHib[(step + 1) * 16 + c0 * 4];
            #pragma unroll
            for (int e = 0; e < 4; ++e) {
                a0.h[e] = __builtin_elementwise_max(a0.h[e] + hib[e], z2);
                a1.h[e] = __builtin_elementwise_max(a1.h[e] + hib[e + 4], z2);
            }
            *(uint4*)&sH[p ^ 1][hj_j * 32 + ((c0 ^ swz) * 8)] = a0.u;
            *(uint4*)&sH[p ^ 1][hj_j * 32 + (((c0 + 1) ^ swz) * 8)] = a1.u;
            if (step < 22) {  // prefetch hj(step+2)
                g0 = *(const uint4*)(hjrow + (step + 2) * 32);
                g1 = *(const uint4*)(hjrow + (step + 2) * 32 + 8);
            }
        }
        // MFMA on current buffers
        half8 aF[4];
        #pragma unroll
        for (int mt = 0; mt < 4; ++mt) {
            int j = wm * 64 + mt * 16 + col;
            aF[mt] = *(const half8*)&sH[p][j * 32 + ((q ^ ((j >> 1) & 3)) * 8)];
        }
        #pragma unroll
        for (int nt = 0; nt < 6; ++nt) {
            half8 bF = *(const half8*)&sW[p][(wn * 6 + nt) * 512 + lane * 8];
            #pragma unroll
            for (int mt = 0; mt < 4; ++mt)
                acc[mt][nt] = mfma16(aF[mt], bF, acc[mt][nt]);
        }
        __syncthreads();
    }

    // epilogue: ew_partial[j] += sum_n relu(U+b2)*w3[n]  (this block's 192 cols)
    #pragma unroll
    for (int mt = 0; mt < 4; ++mt) {
        float s0 = 0.f, s1 = 0.f, s2 = 0.f, s3 = 0.f;
        #pragma unroll
        for (int nt = 0; nt < 6; ++nt) {
            int n = nc * 192 + wn * 96 + nt * 16 + col;
            float w3n = w3[n], b2n = b2[n];
            s0 += fmaxf(acc[mt][nt][0] + b2n, 0.f) * w3n;
            s1 += fmaxf(acc[mt][nt][1] + b2n, 0.f) * w3n;
            s2 += fmaxf(acc[mt][nt][2] + b2n, 0.f) * w3n;
            s3 += fmaxf(acc[mt][nt][3] + b2n, 0.f) * w3n;
        }
        #pragma unroll
        for (int off = 1; off < 16; off <<= 1) {
            s0 += __shfl_xor(s0, off); s1 += __shfl_xor(s1, off);
            s2 += __shfl_xor(s2, off); s3 += __shfl_xor(s3, off);
        }
        if (col == 0) {
            int r = wm * 64 + mt * 16 + q * 4;
            atomicAdd(&sEw[r + 0], s0); atomicAdd(&sEw[r + 1], s1);
            atomicAdd(&sEw[r + 2], s2); atomicAdd(&sEw[r + 3], s3);
        }
    }
    __syncthreads();
    if (t < 128) atomicAdd(&ewg[row_i * 128 + t], sEw[t]);
}

// ---- softmax kernel: ew -> sigmoid -> adj*ew + I -> softmax -> ah (f16) ----
__global__ __launch_bounds__(128) void sm_kernel(
    const float* __restrict__ ewg, const float* __restrict__ b3,
    const float* __restrict__ adj, unsigned short* __restrict__ ah) {
    __shared__ float sRed[4];
    const int row = blockIdx.x, t = threadIdx.x;
    const int i = row & 127;
    const int wave = t >> 6, lane = t & 63;
    float p = ewg[row * 128 + t] + b3[0];
    float ew = 1.f / (1.f + expf(-p));
    float logit = adj[row * 128 + t] * ew + (t == i ? 1.f : 0.f);
    float mx = logit;
    #pragma unroll
    for (int off = 1; off < 64; off <<= 1) mx = fmaxf(mx, __shfl_xor(mx, off));
    if (lane == 0) sRed[wave] = mx;
    __syncthreads();
    mx = fmaxf(sRed[0], sRed[1]);
    float e = expf(logit - mx);
    float sm = e;
    #pragma unroll
    for (int off = 1; off < 64; off <<= 1) sm += __shfl_xor(sm, off);
    if (lane == 0) sRed[2 + wave] = sm;
    __syncthreads();
    float tot = sRed[2] + sRed[3];
    ah[row * 128 + t] = f2h(e / tot);
}

// ---- GCN layer: ax(_LN) = (a+I)@[LN(y_prev)|x]; Y = ax@gw; relu+stats ------
// grid (4 nq, 8 t, 8 b) x 256.  LN fused via A-scaling when gS_in != null.
__global__ __launch_bounds__(256) void gcnA_kernel(
    const unsigned short* __restrict__ ah, const unsigned short* __restrict__ xsrc,
    const unsigned short* __restrict__ yprevT,
    const float* __restrict__ gS_in, const float* __restrict__ gQ_in,
    const float* __restrict__ lng_p, const float* __restrict__ lnb_p,
    const unsigned short* __restrict__ gwp_l, const float* __restrict__ gb_l,
    unsigned short* __restrict__ yT_out, unsigned short* __restrict__ yb_out,
    float* __restrict__ gS_out, float* __restrict__ gQ_out) {
    __shared__ __align__(16) unsigned short sBuf[16 * 776];
    __shared__ float sMu[128], sRstd[128];
    const int nq = blockIdx.x, t0 = blockIdx.y * 16, b = blockIdx.z;
    const int t = threadIdx.x, wave = t >> 6, lane = t & 63;
    const int col = lane & 15, q = lane >> 4;
    const bool hasLN = (gS_in != nullptr);

    if (hasLN) {
        if (t < 128) {
            int row = b * 128 + t;
            float mu = gS_in[row] * (1.f / 768.f);
            float va = gQ_in[row] * (1.f / 768.f) - mu * mu;
            sMu[t] = mu; sRstd[t] = rsqrtf(va + 1e-5f);
        }
        __syncthreads();
    }

    // ---- phase 1 ----
    floatx4 acc1[12];
    #pragma unroll
    for (int nt = 0; nt < 12; ++nt) acc1[nt] = (floatx4){0.f, 0.f, 0.f, 0.f};
    float cp = 0.f;
    {
        const unsigned short* arow = ah + (b * 128 + t0 + col) * 128;
        const int token = t0 + col;
        #pragma unroll
        for (int kc = 0; kc < 4; ++kc) {
            half8 aF1 = *(const half8*)&arow[kc * 32 + q * 8];
            const int kb = kc * 32 + q * 8;
            if (!hasLN) {
                if (token >= kb && token < kb + 8)
                    aF1[token - kb] = (_Float16)((float)aF1[token - kb] + 1.0f);
                #pragma unroll
                for (int nt = 0; nt < 12; ++nt) {
                    half8 bF = *(const half8*)&xsrc[((b * 4 + kc) * 48 + wave * 12 + nt) * 512 + lane * 8];
                    acc1[nt] = mfma16(aF1, bF, acc1[nt]);
                }
            } else {
                #pragma unroll
                for (int e = 0; e < 8; ++e) {
                    int tk = kb + e;
                    float av = (float)aF1[e] + (tk == token ? 1.f : 0.f);
                    float as = av * sRstd[tk];
                    cp += as * sMu[tk];
                    aF1[e] = (_Float16)as;
                }
                #pragma unroll
                for (int nt = 0; nt < 12; ++nt) {
                    int n = wave * 192 + nt * 16 + col;
                    half8 bF = *(const half8*)&yprevT[(b * 768 + n) * 128 + kc * 32 + q * 8];
                    acc1[nt] = mfma16(aF1, bF, acc1[nt]);
                }
            }
        }
    }
    float cR[4] = {0.f, 0.f, 0.f, 0.f};
    if (hasLN) {
        cp += __shfl_xor(cp, 16); cp += __shfl_xor(cp, 32);
        #pragma unroll
        for (int r = 0; r < 4; ++r) cR[r] = __shfl(cp, q * 4 + r);
    }
    // ax(_LN) -> sBuf in A-layout (row-major, stride 776)
    #pragma unroll
    for (int nt = 0; nt < 12; ++nt) {
        int n = wave * 192 + nt * 16 + col;
        float lg = hasLN ? lng_p[n] : 0.f;
        float lb = hasLN ? lnb_p[n] : 0.f;
        #pragma unroll
        for (int r = 0; r < 4; ++r) {
            float v = acc1[nt][r];
            if (hasLN) v = lg * (v - cR[r]) + 2.f * lb;
            sBuf[(q * 4 + r) * 776 + n] = f2h(v);
        }
    }
    __syncthreads();

    // ---- phase 2: Y quarter nq (explicit bF prefetch; 1 block/CU) ----
    floatx4 acc2[3];
    #pragma unroll
    for (int nt = 0; nt < 3; ++nt) acc2[nt] = (floatx4){0.f, 0.f, 0.f, 0.f};
    const int ntg0 = nq * 12 + wave * 3;
    half8 bn[3];
    #pragma unroll
    for (int nt = 0; nt < 3; ++nt)
        bn[nt] = *(const half8*)&gwp_l[(0 * 48 + ntg0 + nt) * 512 + lane * 8];
    for (int s = 0; s < 24; ++s) {
        half8 bc[3];
        #pragma unroll
        for (int nt = 0; nt < 3; ++nt) bc[nt] = bn[nt];
        if (s < 23) {
            #pragma unroll
            for (int nt = 0; nt < 3; ++nt)
                bn[nt] = *(const half8*)&gwp_l[((s + 1) * 48 + ntg0 + nt) * 512 + lane * 8];
        }
        half8 aF = *(const half8*)&sBuf[col * 776 + s * 32 + q * 8];
        #pragma unroll
        for (int nt = 0; nt < 3; ++nt) acc2[nt] = mfma16(aF, bc[nt], acc2[nt]);
    }

    // epilogue: v = relu(Y*0.5 + gb); store yT (packed) or yb (row-major); stats
    float ps[4] = {0.f, 0.f, 0.f, 0.f}, pq[4] = {0.f, 0.f, 0.f, 0.f};
    #pragma unroll
    for (int nt = 0; nt < 3; ++nt) {
        int n = nq * 192 + wave * 48 + nt * 16 + col;
        float g = gb_l[n];
        float v[4];
        #pragma unroll
        for (int r = 0; r < 4; ++r) {
            v[r] = fmaxf(acc2[nt][r] * 0.5f + g, 0.f);
            ps[r] += v[r]; pq[r] += v[r] * v[r];
        }
        if (yT_out) {
            union { half2v h[2]; uint2 u; } pk;
            pk.h[0] = f2h2v(v[0], v[1]);
            pk.h[1] = f2h2v(v[2], v[3]);
            *(uint2*)&yT_out[(b * 768 + n) * 128 + t0 + q * 4] = pk.u;
        } else {
            #pragma unroll
            for (int r = 0; r < 4; ++r)
                yb_out[(b * 128 + t0 + q * 4 + r) * 768 + n] = f2h(v[r]);
        }
    }
    #pragma unroll
    for (int off = 1; off < 16; off <<= 1) {
        #pragma unroll
        for (int r = 0; r < 4; ++r) {
            ps[r] += __shfl_xor(ps[r], off);
            pq[r] += __shfl_xor(pq[r], off);
        }
    }
    if (col == 0) {
        #pragma unroll
        for (int r = 0; r < 4; ++r) {
            int row = b * 128 + t0 + q * 4 + r;
            atomicAdd(&gS_out[row], ps[r]);
            atomicAdd(&gQ_out[row], pq[r]);
        }
    }
}

// ---- final LN: normalize y3 and write fp32 output --------------------------
__global__ __launch_bounds__(128) void gcnBfin_kernel(
    const unsigned short* __restrict__ yb, const float* __restrict__ gS,
    const float* __restrict__ gQ, const float* __restrict__ lng_l,
    const float* __restrict__ lnb_l, float* __restrict__ outf) {
    const int row = blockIdx.x, t = threadIdx.x;
    const float mu = gS[row] * (1.f / 768.f);
    const float va = gQ[row] * (1.f / 768.f) - mu * mu;
    const float rstd = rsqrtf(va + 1e-5f);
    if (t < 96) {
        union { uint4 u; unsigned short s[8]; } v;
        v.u = *(const uint4*)&yb[row * 768 + t * 8];
        #pragma unroll
        for (int e = 0; e < 8; ++e) {
            int d = t * 8 + e;
            outf[row * 768 + d] = (h2f(v.s[e]) - mu) * rstd * lng_l[d] + lnb_l[d];
        }
    }
}

// ------------------------------- launch -------------------------------------
extern "C" void kernel_launch(void* const* d_in, const int* in_sizes, int n_in,
                              void* d_out, int out_size, void* d_ws, size_t ws_size,
                              hipStream_t stream) {
    const float* adj = (const float*)d_in[0];
    const float* x   = (const float*)d_in[1];
    const float* w1  = (const float*)d_in[2];
    const float* b1  = (const float*)d_in[3];
    const float* w2  = (const float*)d_in[4];
    const float* b2  = (const float*)d_in[5];
    const float* w3  = (const float*)d_in[6];
    const float* b3  = (const float*)d_in[7];
    const float* gw  = (const float*)d_in[8];
    const float* gb  = (const float*)d_in[9];
    const float* lng = (const float*)d_in[10];
    const float* lnb = (const float*)d_in[11];
    float* outp = (float*)d_out;  // 786432 out + 1024 mask

    char* ws = (char*)d_ws;
    unsigned short* w1t = (unsigned short*)(ws + 0);         // 1536x768 f16 [n][k]
    unsigned short* w2p = (unsigned short*)(ws + 2359296);   // 24x24x512 frag
    unsigned short* gwp = (unsigned short*)(ws + 2949120);   // 3x(24x48x512) frag
    unsigned short* xh  = (unsigned short*)(ws + 6488064);   // 1024x768 f16
    float*          hi  = (float*)        (ws + 8060928);    // 1024x768 fp32
    unsigned short* hjh = (unsigned short*)(ws + 11206656);  // 1024x768 f16
    unsigned short* ah  = (unsigned short*)(ws + 12779520);  // 8x128x128 f16
    unsigned short* xpk = (unsigned short*)(ws + 13041664);  // 8x4x48x512 frag
    unsigned short* yb  = (unsigned short*)(ws + 14614528);  // 1024x768 f16
    float*          ewg = (float*)        (ws + 16187392);   // 1024x128 f32
    // aliases over dead regions:
    float* stats = (float*)(ws + 6488064);                   // 3x(gS|gQ), over xh
    unsigned short* y1T = (unsigned short*)(ws + 0);         // over w1t
    unsigned short* y2T = (unsigned short*)(ws + 8060928);   // over hi

    prep_kernel<<<dim3(24, 24, 15), dim3(32, 8), 0, stream>>>(
        x, w1, w2, gw, w1t, w2p, gwp, xh, xpk, ewg, outp + 786432);
    gemm128_kernel<<<dim3(12, 8), 256, 0, stream>>>(xh, w1t, hi, hjh);
    edge_kernel<<<dim3(1024, 2), 256, 0, stream>>>(hi, hjh, b1, w2p, b2, w3, ewg, stats);
    sm_kernel<<<1024, 128, 0, stream>>>(ewg, b3, adj, ah);

    float* S1 = stats,        *Q1 = stats + 1024;
    float* S2 = stats + 2048, *Q2 = stats + 3072;
    float* S3 = stats + 4096, *Q3 = stats + 5120;

    // layer 1: src = x (packed), no LN; out y1T + stats1
    gcnA_kernel<<<dim3(4, 8, 8), 256, 0, stream>>>(
        ah, xpk, nullptr, nullptr, nullptr, nullptr, nullptr,
        gwp, gb, y1T, nullptr, S1, Q1);
    // layer 2: src = LN(y1) fused; out y2T + stats2
    gcnA_kernel<<<dim3(4, 8, 8), 256, 0, stream>>>(
        ah, nullptr, y1T, S1, Q1, lng, lnb,
        gwp + 589824, gb + 768, y2T, nullptr, S2, Q2);
    // layer 3: src = LN(y2) fused; out yb row-major + stats3
    gcnA_kernel<<<dim3(4, 8, 8), 256, 0, stream>>>(
        ah, nullptr, y2T, S2, Q2, lng + 768, lnb + 768,
        gwp + 1179648, gb + 1536, nullptr, yb, S3, Q3);
    // final LN -> fp32 output
    gcnBfin_kernel<<<1024, 128, 0, stream>>>(yb, S3, Q3, lng + 1536, lnb + 1536, outp);
}